// Round 8
// baseline (666.779 us; speedup 1.0000x reference)
//
#include <hip/hip_runtime.h>

#define Nn 50000
#define Ee 800000
#define Gg 1000
#define Hh 128
#define Cc 6
#define EPSf 1e-5f
#define SB 1024                       // elements per scan block
#define NSB ((Nn + SB - 1) / SB)      // 49
#define NSLICE 8                      // channel slices (16 ch each), XCD-affine

typedef unsigned short u16;
typedef unsigned int u32;
typedef __attribute__((ext_vector_type(8))) short bf16x8;
typedef __attribute__((ext_vector_type(4))) float f32x4;

static __device__ inline u16 f2bf(float f) {
    u32 u = __float_as_uint(f);
    u32 r = (u + 0x7fffu + ((u >> 16) & 1u)) >> 16;   // RNE
    return (u16)r;
}
static __device__ inline float bf_lo(u32 v) { return __uint_as_float(v << 16); }
static __device__ inline float bf_hi(u32 v) { return __uint_as_float(v & 0xffff0000u); }

// ---------------- fused prologue: zero indeg+stats, cast x->bf16, W->bf16 W^T ----------------
__global__ __launch_bounds__(256) void k_pre(const float* __restrict__ X,
                                             u16* __restrict__ Xh,
                                             const float* __restrict__ W3,
                                             u16* __restrict__ WT3,
                                             int* __restrict__ indeg,
                                             float* __restrict__ stats3) {
    int t = blockIdx.x * blockDim.x + threadIdx.x;
    if (t < Nn * 32) {                 // cast x (float4 granular)
        float4 v = ((const float4*)X)[t];
        ushort4 o;
        o.x = f2bf(v.x); o.y = f2bf(v.y); o.z = f2bf(v.z); o.w = f2bf(v.w);
        ((ushort4*)Xh)[t] = o;
    }
    if (t < Nn) indeg[t] = 0;
    if (t < 3 * 2 * Hh) stats3[t] = 0.0f;

    if (blockIdx.x < 3) {              // weight transpose for layer l = blockIdx.x
        __shared__ u16 tbuf[Hh * 136];
        int l = blockIdx.x;
        const float* W = W3 + l * Hh * Hh;
        u16* WT = WT3 + l * Hh * Hh;
        int tid = threadIdx.x;
#pragma unroll
        for (int i = 0; i < 16; i++) {
            int v = tid + 256 * i;     // float4 idx over 4096
            int r = v >> 5, c4 = v & 31;
            float4 d = ((const float4*)W)[v];
            u16* p = tbuf + r * 136 + c4 * 4;
            p[0] = f2bf(d.x); p[1] = f2bf(d.y); p[2] = f2bf(d.z); p[3] = f2bf(d.w);
        }
        __syncthreads();
#pragma unroll
        for (int i = 0; i < 64; i++) {
            int o = tid + 256 * i;     // u16 idx over 16384
            int n = o >> 7, k = o & 127;
            WT[o] = tbuf[k * 136 + n];
        }
    }
}

// ---------------- in-degree histogram ----------------
__global__ void k_deg(const int* __restrict__ ei, int* __restrict__ indeg) {
    int e = blockIdx.x * blockDim.x + threadIdx.x;
    if (e < Ee) atomicAdd(&indeg[ei[Ee + e]], 1);
}

// ---------------- scan phase 1 + dis + gstart (fused) ----------------
__global__ __launch_bounds__(256) void k_scan1(const int* __restrict__ indeg,
                                               int* __restrict__ rs,
                                               int* __restrict__ bsum,
                                               float* __restrict__ dis,
                                               const int* __restrict__ batch,
                                               int* __restrict__ gstart) {
    __shared__ int ts[256];
    int b = blockIdx.x;
    int t = threadIdx.x;
    int base = b * SB + t * 4;
    int v[4] = {0, 0, 0, 0};
#pragma unroll
    for (int j = 0; j < 4; j++) {
        int i = base + j;
        if (i < Nn) { v[j] = indeg[i]; dis[i] = rsqrtf((float)v[j] + 1.0f); }
    }
    int g = b * 256 + t;
    if (g <= Gg) {
        int lo = 0, hi = Nn;
        while (lo < hi) {
            int mid = (lo + hi) >> 1;
            if (batch[mid] < g) lo = mid + 1; else hi = mid;
        }
        gstart[g] = lo;
    }
    int tsum = v[0] + v[1] + v[2] + v[3];
    ts[t] = tsum;
    __syncthreads();
    for (int off = 1; off < 256; off <<= 1) {
        int x = (t >= off) ? ts[t - off] : 0;
        __syncthreads();
        ts[t] += x;
        __syncthreads();
    }
    int run = (t == 0) ? 0 : ts[t - 1];
    if (t == 255) bsum[b] = ts[255];
#pragma unroll
    for (int j = 0; j < 4; j++) {
        int i = base + j;
        if (i < Nn) { rs[i] = run; run += v[j]; }
    }
}

// ---------------- scan phase 2: per-block redundant top-scan + add ----------------
__global__ __launch_bounds__(256) void k_scan2(int* __restrict__ rs,
                                               const int* __restrict__ bsum) {
    __shared__ int lboff[NSB];
    int t = threadIdx.x;
    if (t < 64) {
        int orig = (t < NSB) ? bsum[t] : 0;
        int v = orig;
#pragma unroll
        for (int off = 1; off < 64; off <<= 1) {
            int u = __shfl_up(v, off, 64);
            if (t >= off) v += u;
        }
        if (t < NSB) lboff[t] = v - orig;   // exclusive
    }
    __syncthreads();
    int i = blockIdx.x * blockDim.x + t;
    if (i < Nn) rs[i] += lboff[i >> 10];
}

// ---------------- counting-sort fill: 4B packed {w:bf16 | src:u16} ----------------
// After this kernel rs[d] == end of segment d.
__global__ void k_fill(const int* __restrict__ ei, int* __restrict__ rs,
                       const float* __restrict__ dis, u32* __restrict__ recs) {
    int e = blockIdx.x * blockDim.x + threadIdx.x;
    if (e >= Ee) return;
    int s = ei[e];
    int d = ei[Ee + e];
    int slot = atomicAdd(&rs[d], 1);
    float w = dis[s] * dis[d];
    recs[slot] = ((u32)f2bf(w) << 16) | (u32)s;   // s < 50000 < 65536
}

// ---------------- MFMA GEMM: YhS (slice-major bf16) = Xh(bf16) @ W ----------------
// Output layout: YhS[slice][node][16ch]; slice == N-tile index t.
__global__ __launch_bounds__(256) void k_gemm(const u16* __restrict__ Xh,
                                              const u16* __restrict__ WT,
                                              u16* __restrict__ YhS) {
    __shared__ u16 wt[Hh * 136];
    int tid = threadIdx.x;
#pragma unroll
    for (int i = 0; i < 8; i++) {
        int v = tid + 256 * i;            // uint4 idx over 2048
        int n = v >> 4, k8 = v & 15;
        uint4 d = ((const uint4*)WT)[v];
        *((uint4*)(wt + n * 136 + k8 * 8)) = d;
    }
    __syncthreads();

    int wv = tid >> 6, lane = tid & 63;
    int m = lane & 15, q = lane >> 4;
    int row0 = blockIdx.x * 64 + wv * 16;
    int lrow = row0 + m;
    if (lrow >= Nn) lrow = Nn - 1;        // clamp load row; stores guarded
    const u16* xrow = Xh + lrow * Hh + q * 8;

    f32x4 acc[8] = {};
#pragma unroll
    for (int k0 = 0; k0 < Hh; k0 += 32) {
        bf16x8 a = *(const bf16x8*)(xrow + k0);
#pragma unroll
        for (int t = 0; t < 8; t++) {
            bf16x8 b = *(const bf16x8*)(wt + (t * 16 + m) * 136 + k0 + q * 8);
            acc[t] = __builtin_amdgcn_mfma_f32_16x16x32_bf16(a, b, acc[t], 0, 0, 0);
        }
    }

    int orow0 = row0 + q * 4;
#pragma unroll
    for (int t = 0; t < 8; t++) {
#pragma unroll
        for (int r = 0; r < 4; r++) {
            int rr = orow0 + r;
            if (rr < Nn) YhS[(size_t)t * (Nn * 16) + rr * 16 + m] = f2bf(acc[t][r]);
        }
    }
}

// ---------------- sliced CSR gather: one wave per (node, slice); XCD-affine ----------------
// blockIdx = nodeblock*8 + slice -> round-robin dispatch puts each slice on one XCD,
// whose 1.6MB slice working set fits the 4MB per-XCD L2.
__global__ __launch_bounds__(256) void k_gather(const u16* __restrict__ YhS,
                                                const float* __restrict__ dis,
                                                const float* __restrict__ bias,
                                                const int* __restrict__ rs,
                                                const u32* __restrict__ recs,
                                                u16* __restrict__ AhS) {
    int s = blockIdx.x & (NSLICE - 1);
    int nb = blockIdx.x >> 3;
    int wv = threadIdx.x >> 6, lane = threadIdx.x & 63;
    int node = nb * 4 + wv;
    if (node >= Nn) return;
    int g = lane >> 3, m2 = lane & 7;

    const u32* base = (const u32*)YhS + (size_t)s * (Nn * 8);
    float dn = dis[node];
    float2 acc = {0.0f, 0.0f};
    if (g == 0) {                         // self-loop + bias only once
        u32 hv = base[node * 8 + m2];
        float2 bv = ((const float2*)bias)[s * 8 + m2];
        float sn = dn * dn;
        acc.x = bf_lo(hv) * sn + bv.x;
        acc.y = bf_hi(hv) * sn + bv.y;
    }

    int beg = (node == 0) ? 0 : rs[node - 1];
    int end = rs[node];
    for (int j = beg + g; j < end; j += 8) {
        u32 rec = recs[j];
        int src = rec & 0xffffu;
        float w = __uint_as_float(rec & 0xffff0000u);
        u32 v = base[src * 8 + m2];
        acc.x += bf_lo(v) * w;
        acc.y += bf_hi(v) * w;
    }
    // reduce across the 8 edge-groups (lanes with equal m2)
#pragma unroll
    for (int off = 8; off < 64; off <<= 1) {
        acc.x += __shfl_xor(acc.x, off, 64);
        acc.y += __shfl_xor(acc.y, off, 64);
    }
    if (g == 0) {
        u32 o = ((u32)f2bf(acc.y) << 16) | (u32)f2bf(acc.x);
        ((u32*)AhS)[(size_t)s * (Nn * 8) + node * 8 + m2] = o;
    }
}

// ---------------- BN stats from slice-major bf16: per-channel sum & sumsq ----------------
__global__ __launch_bounds__(256) void k_stats(const u16* __restrict__ AhS,
                                               float* __restrict__ stats) {
    __shared__ float sh[4][256];
    int t = threadIdx.x;
    int jc = t & 63, ro = t >> 6;         // jc: u32-column (slice*8+m2), ro: row offset
    int s = jc >> 3, m2 = jc & 7;
    const u32* col = (const u32*)AhS + (size_t)s * (Nn * 8) + m2;
    float sx = 0.f, sy = 0.f, qx = 0.f, qy = 0.f;
    for (int r = blockIdx.x * 4 + ro; r < Nn; r += 1024) {
        u32 v = col[r * 8];
        float a = bf_lo(v), b = bf_hi(v);
        sx += a; sy += b; qx += a * a; qy += b * b;
    }
    sh[0][t] = sx; sh[1][t] = sy; sh[2][t] = qx; sh[3][t] = qy;
    __syncthreads();
    if (t < 64) {
        sx = sh[0][t] + sh[0][t + 64] + sh[0][t + 128] + sh[0][t + 192];
        sy = sh[1][t] + sh[1][t + 64] + sh[1][t + 128] + sh[1][t + 192];
        qx = sh[2][t] + sh[2][t + 64] + sh[2][t + 128] + sh[2][t + 192];
        qy = sh[3][t] + sh[3][t + 64] + sh[3][t + 128] + sh[3][t + 192];
        int c0 = (t >> 3) * 16 + (t & 7) * 2;
        atomicAdd(&stats[c0], sx);
        atomicAdd(&stats[c0 + 1], sy);
        atomicAdd(&stats[Hh + c0], qx);
        atomicAdd(&stats[Hh + c0 + 1], qy);
    }
}

// ---------------- BN normalize + affine + relu; slice-major bf16 in ----------------
// out: bf16 row-major Xh (layers 0,1) OR fp32 row-major Xo (layer 2)
__global__ void k_norm(const u16* __restrict__ AhS, const float* __restrict__ stats,
                       const float* __restrict__ gam, const float* __restrict__ bet,
                       float* __restrict__ Xo, u16* __restrict__ Xh, int wf32) {
    int tid = blockIdx.x * blockDim.x + threadIdx.x;
    if (tid >= Nn * 32) return;
    int n = tid >> 5, c4 = tid & 31;      // c4 covers channels 4c4..4c4+3
    int s = c4 >> 2, m2 = (c4 & 3) * 2;
    const u32* p = (const u32*)AhS + (size_t)s * (Nn * 8) + n * 8 + m2;
    uint2 a = *(const uint2*)p;
    float vv[4] = { bf_lo(a.x), bf_hi(a.x), bf_lo(a.y), bf_hi(a.y) };
    float4 o;
#pragma unroll
    for (int j = 0; j < 4; j++) {
        int c = c4 * 4 + j;
        float mu = stats[c] * (1.0f / Nn);
        float var = stats[Hh + c] * (1.0f / Nn) - mu * mu;
        float istd = rsqrtf(var + EPSf);
        float val = (vv[j] - mu) * istd * gam[c] + bet[c];
        (&o.x)[j] = fmaxf(val, 0.0f);
    }
    if (wf32) {
        ((float4*)Xo)[tid] = o;
    } else {
        ushort4 h;
        h.x = f2bf(o.x); h.y = f2bf(o.y); h.z = f2bf(o.z); h.w = f2bf(o.w);
        ((ushort4*)Xh)[tid] = h;
    }
}

// ---------------- fused segmented mean pool + MLP head: one block per graph ----------------
__global__ __launch_bounds__(128) void k_poolmlp(const float* __restrict__ X,
                                                 const int* __restrict__ gstart,
                                                 const float* __restrict__ W1,
                                                 const float* __restrict__ b1,
                                                 const float* __restrict__ W2,
                                                 const float* __restrict__ b2,
                                                 float* __restrict__ out) {
    int g = blockIdx.x;
    int c = threadIdx.x;
    __shared__ float p[Hh];
    __shared__ float hid[Hh];
    int s = gstart[g], e = gstart[g + 1];
    float sum = 0.0f;
    for (int r = s; r < e; r++) sum += X[r * Hh + c];
    int n = e - s;
    p[c] = sum / (float)(n > 1 ? n : 1);
    __syncthreads();
    float acc = b1[c];
    for (int k = 0; k < Hh; k++) acc += p[k] * W1[k * Hh + c];
    hid[c] = fmaxf(acc, 0.0f);
    __syncthreads();
    if (c < Cc) {
        float acc2 = b2[c];
        for (int k = 0; k < Hh; k++) acc2 += hid[k] * W2[k * Cc + c];
        out[g * Cc + c] = acc2;
    }
}

extern "C" void kernel_launch(void* const* d_in, const int* in_sizes, int n_in,
                              void* d_out, int out_size, void* d_ws, size_t ws_size,
                              hipStream_t stream) {
    const float* x      = (const float*)d_in[0];
    const int*   ei     = (const int*)d_in[1];
    const int*   batch  = (const int*)d_in[2];
    const float* conv_w = (const float*)d_in[3];
    const float* conv_b = (const float*)d_in[4];
    const float* bn_g   = (const float*)d_in[5];
    const float* bn_b   = (const float*)d_in[6];
    const float* w1     = (const float*)d_in[7];
    const float* b1     = (const float*)d_in[8];
    const float* w2     = (const float*)d_in[9];
    const float* b2     = (const float*)d_in[10];
    float* out = (float*)d_out;

    // B1 (fp32, layer-2 output for pooling) aliases Xh (bf16 gemm input):
    // Xh is dead after gemm[l=2] completes; norm[l=2] then writes B1.
    float* B1      = (float*)d_ws;                // N*H fp32  (aliases Xh region)
    u16*   Xh      = (u16*)d_ws;                  // N*H bf16  (first half of B1 region)
    u16*   YhS     = (u16*)(B1 + Nn * Hh);        // N*H bf16, slice-major (gemm out)
    u16*   AhS     = YhS + Nn * Hh;               // N*H bf16, slice-major (gather out)
    u16*   WT      = AhS + Nn * Hh;               // 3*H*H bf16 (W^T)
    float* dis     = (float*)(WT + 3 * Hh * Hh);  // N
    float* stats3  = dis + Nn;                    // 3*2*H
    int*   indeg   = (int*)(stats3 + 3 * 2 * Hh); // N
    int*   rs      = indeg + Nn;                  // N
    int*   gstart  = rs + Nn;                     // G+1
    int*   bsum    = gstart + Gg + 1;             // NSB
    u32*   recs    = (u32*)(bsum + NSB);          // E packed 4B records

    // ---- fused prologue + CSR build ----
    k_pre<<<(Nn * 32 + 255) / 256, 256, 0, stream>>>(x, Xh, conv_w, WT, indeg, stats3);
    k_deg<<<(Ee + 255) / 256, 256, 0, stream>>>(ei, indeg);
    k_scan1<<<NSB, 256, 0, stream>>>(indeg, rs, bsum, dis, batch, gstart);
    k_scan2<<<(Nn + 255) / 256, 256, 0, stream>>>(rs, bsum);
    k_fill<<<(Ee + 255) / 256, 256, 0, stream>>>(ei, rs, dis, recs);

    for (int l = 0; l < 3; l++) {
        float* stats = stats3 + l * 2 * Hh;
        k_gemm<<<(Nn + 63) / 64, 256, 0, stream>>>(Xh, WT + l * Hh * Hh, YhS);
        k_gather<<<((Nn + 3) / 4) * NSLICE, 256, 0, stream>>>(YhS, dis, conv_b + l * Hh,
                                                              rs, recs, AhS);
        k_stats<<<256, 256, 0, stream>>>(AhS, stats);
        k_norm<<<(Nn * 32 + 255) / 256, 256, 0, stream>>>(
            AhS, stats, bn_g + l * Hh, bn_b + l * Hh,
            B1, Xh, (l == 2) ? 1 : 0);
    }

    k_poolmlp<<<Gg, 128, 0, stream>>>(B1, gstart, w1, b1, w2, b2, out);
}

// Round 9
// 437.967 us; speedup vs baseline: 1.5224x; 1.5224x over previous
//
#include <hip/hip_runtime.h>

#define Nn 50000
#define Ee 800000
#define Gg 1000
#define Hh 128
#define Cc 6
#define EPSf 1e-5f
#define SB 1024                       // elements per scan block
#define NSB ((Nn + SB - 1) / SB)      // 49

typedef unsigned short u16;
typedef unsigned int u32;
typedef __attribute__((ext_vector_type(8))) short bf16x8;
typedef __attribute__((ext_vector_type(4))) float f32x4;

static __device__ inline u16 f2bf(float f) {
    u32 u = __float_as_uint(f);
    u32 r = (u + 0x7fffu + ((u >> 16) & 1u)) >> 16;   // RNE
    return (u16)r;
}
static __device__ inline float bf_lo(u32 v) { return __uint_as_float(v << 16); }
static __device__ inline float bf_hi(u32 v) { return __uint_as_float(v & 0xffff0000u); }

// ---------------- fused prologue: zero indeg+stats, cast x->bf16, W->bf16 W^T ----------------
__global__ __launch_bounds__(256) void k_pre(const float* __restrict__ X,
                                             u16* __restrict__ Xh,
                                             const float* __restrict__ W3,
                                             u16* __restrict__ WT3,
                                             int* __restrict__ indeg,
                                             float* __restrict__ stats3) {
    int t = blockIdx.x * blockDim.x + threadIdx.x;
    if (t < Nn * 32) {                 // cast x (float4 granular)
        float4 v = ((const float4*)X)[t];
        ushort4 o;
        o.x = f2bf(v.x); o.y = f2bf(v.y); o.z = f2bf(v.z); o.w = f2bf(v.w);
        ((ushort4*)Xh)[t] = o;
    }
    if (t < Nn) indeg[t] = 0;
    if (t < 3 * 2 * Hh) stats3[t] = 0.0f;

    if (blockIdx.x < 3) {              // weight transpose for layer l = blockIdx.x
        __shared__ u16 tbuf[Hh * 136];
        int l = blockIdx.x;
        const float* W = W3 + l * Hh * Hh;
        u16* WT = WT3 + l * Hh * Hh;
        int tid = threadIdx.x;
#pragma unroll
        for (int i = 0; i < 16; i++) {
            int v = tid + 256 * i;     // float4 idx over 4096
            int r = v >> 5, c4 = v & 31;
            float4 d = ((const float4*)W)[v];
            u16* p = tbuf + r * 136 + c4 * 4;
            p[0] = f2bf(d.x); p[1] = f2bf(d.y); p[2] = f2bf(d.z); p[3] = f2bf(d.w);
        }
        __syncthreads();
#pragma unroll
        for (int i = 0; i < 64; i++) {
            int o = tid + 256 * i;     // u16 idx over 16384
            int n = o >> 7, k = o & 127;
            WT[o] = tbuf[k * 136 + n];
        }
    }
}

// ---------------- in-degree histogram ----------------
__global__ void k_deg(const int* __restrict__ ei, int* __restrict__ indeg) {
    int e = blockIdx.x * blockDim.x + threadIdx.x;
    if (e < Ee) atomicAdd(&indeg[ei[Ee + e]], 1);
}

// ---------------- scan phase 1 + dis + gstart (fused) ----------------
__global__ __launch_bounds__(256) void k_scan1(const int* __restrict__ indeg,
                                               int* __restrict__ rs,
                                               int* __restrict__ bsum,
                                               float* __restrict__ dis,
                                               const int* __restrict__ batch,
                                               int* __restrict__ gstart) {
    __shared__ int ts[256];
    int b = blockIdx.x;
    int t = threadIdx.x;
    int base = b * SB + t * 4;
    int v[4] = {0, 0, 0, 0};
#pragma unroll
    for (int j = 0; j < 4; j++) {
        int i = base + j;
        if (i < Nn) { v[j] = indeg[i]; dis[i] = rsqrtf((float)v[j] + 1.0f); }
    }
    int g = b * 256 + t;
    if (g <= Gg) {
        int lo = 0, hi = Nn;
        while (lo < hi) {
            int mid = (lo + hi) >> 1;
            if (batch[mid] < g) lo = mid + 1; else hi = mid;
        }
        gstart[g] = lo;
    }
    int tsum = v[0] + v[1] + v[2] + v[3];
    ts[t] = tsum;
    __syncthreads();
    for (int off = 1; off < 256; off <<= 1) {
        int x = (t >= off) ? ts[t - off] : 0;
        __syncthreads();
        ts[t] += x;
        __syncthreads();
    }
    int run = (t == 0) ? 0 : ts[t - 1];
    if (t == 255) bsum[b] = ts[255];
#pragma unroll
    for (int j = 0; j < 4; j++) {
        int i = base + j;
        if (i < Nn) { rs[i] = run; run += v[j]; }
    }
}

// ---------------- scan phase 2: per-block redundant top-scan + add ----------------
__global__ __launch_bounds__(256) void k_scan2(int* __restrict__ rs,
                                               const int* __restrict__ bsum) {
    __shared__ int lboff[NSB];
    int t = threadIdx.x;
    if (t < 64) {
        int orig = (t < NSB) ? bsum[t] : 0;
        int v = orig;
#pragma unroll
        for (int off = 1; off < 64; off <<= 1) {
            int u = __shfl_up(v, off, 64);
            if (t >= off) v += u;
        }
        if (t < NSB) lboff[t] = v - orig;   // exclusive
    }
    __syncthreads();
    int i = blockIdx.x * blockDim.x + t;
    if (i < Nn) rs[i] += lboff[i >> 10];
}

// ---------------- counting-sort fill: 4B packed {w:bf16 | src:u16} ----------------
// After this kernel rs[d] == end of segment d.
__global__ void k_fill(const int* __restrict__ ei, int* __restrict__ rs,
                       const float* __restrict__ dis, u32* __restrict__ recs) {
    int e = blockIdx.x * blockDim.x + threadIdx.x;
    if (e >= Ee) return;
    int s = ei[e];
    int d = ei[Ee + e];
    int slot = atomicAdd(&rs[d], 1);
    float w = dis[s] * dis[d];
    recs[slot] = ((u32)f2bf(w) << 16) | (u32)s;   // s < 50000 < 65536
}

// ---------------- MFMA GEMM: Yh[N,H](bf16 row-major) = Xh(bf16) @ W ----------------
__global__ __launch_bounds__(256) void k_gemm(const u16* __restrict__ Xh,
                                              const u16* __restrict__ WT,
                                              u16* __restrict__ Yh) {
    __shared__ u16 wt[Hh * 136];
    int tid = threadIdx.x;
#pragma unroll
    for (int i = 0; i < 8; i++) {
        int v = tid + 256 * i;            // uint4 idx over 2048
        int n = v >> 4, k8 = v & 15;
        uint4 d = ((const uint4*)WT)[v];
        *((uint4*)(wt + n * 136 + k8 * 8)) = d;
    }
    __syncthreads();

    int wv = tid >> 6, lane = tid & 63;
    int m = lane & 15, q = lane >> 4;
    int row0 = blockIdx.x * 64 + wv * 16;
    int lrow = row0 + m;
    if (lrow >= Nn) lrow = Nn - 1;        // clamp load row; stores guarded
    const u16* xrow = Xh + lrow * Hh + q * 8;

    f32x4 acc[8] = {};
#pragma unroll
    for (int k0 = 0; k0 < Hh; k0 += 32) {
        bf16x8 a = *(const bf16x8*)(xrow + k0);
#pragma unroll
        for (int t = 0; t < 8; t++) {
            bf16x8 b = *(const bf16x8*)(wt + (t * 16 + m) * 136 + k0 + q * 8);
            acc[t] = __builtin_amdgcn_mfma_f32_16x16x32_bf16(a, b, acc[t], 0, 0, 0);
        }
    }

    int orow0 = row0 + q * 4;
#pragma unroll
    for (int t = 0; t < 8; t++) {
#pragma unroll
        for (int r = 0; r < 4; r++) {
            int rr = orow0 + r;
            if (rr < Nn) Yh[rr * Hh + t * 16 + m] = f2bf(acc[t][r]);
        }
    }
}

// ---------------- CSR gather: one wave/node, bf16 rows, 4B recs, unroll 8 ----------------
// Writes bf16 packed aggregation rows (row-major).
__global__ __launch_bounds__(256) void k_gather(const u16* __restrict__ Yh,
                                                const float* __restrict__ dis,
                                                const float* __restrict__ bias,
                                                const int* __restrict__ rs,
                                                const u32* __restrict__ recs,
                                                u16* __restrict__ Ah) {
    int node = blockIdx.x * 4 + (threadIdx.x >> 6);
    if (node >= Nn) return;
    int lane = threadIdx.x & 63;

    const u32* rows = (const u32*)Yh;
    float dn = dis[node];
    u32 hv = rows[node * 64 + lane];
    float2 bv = ((const float2*)bias)[lane];
    float sn = dn * dn;
    float2 acc;
    acc.x = bf_lo(hv) * sn + bv.x;
    acc.y = bf_hi(hv) * sn + bv.y;

    int beg = (node == 0) ? 0 : rs[node - 1];
    int end = rs[node];

    int j = beg;
    for (; j + 7 < end; j += 8) {
        u32 r0 = recs[j],     r1 = recs[j + 1];
        u32 r2 = recs[j + 2], r3 = recs[j + 3];
        u32 r4 = recs[j + 4], r5 = recs[j + 5];
        u32 r6 = recs[j + 6], r7 = recs[j + 7];
        u32 v0 = rows[(r0 & 0xffffu) * 64 + lane];
        u32 v1 = rows[(r1 & 0xffffu) * 64 + lane];
        u32 v2 = rows[(r2 & 0xffffu) * 64 + lane];
        u32 v3 = rows[(r3 & 0xffffu) * 64 + lane];
        u32 v4 = rows[(r4 & 0xffffu) * 64 + lane];
        u32 v5 = rows[(r5 & 0xffffu) * 64 + lane];
        u32 v6 = rows[(r6 & 0xffffu) * 64 + lane];
        u32 v7 = rows[(r7 & 0xffffu) * 64 + lane];
        float w0 = __uint_as_float(r0 & 0xffff0000u);
        float w1 = __uint_as_float(r1 & 0xffff0000u);
        float w2 = __uint_as_float(r2 & 0xffff0000u);
        float w3 = __uint_as_float(r3 & 0xffff0000u);
        float w4 = __uint_as_float(r4 & 0xffff0000u);
        float w5 = __uint_as_float(r5 & 0xffff0000u);
        float w6 = __uint_as_float(r6 & 0xffff0000u);
        float w7 = __uint_as_float(r7 & 0xffff0000u);
        acc.x += bf_lo(v0) * w0 + bf_lo(v1) * w1 + bf_lo(v2) * w2 + bf_lo(v3) * w3
               + bf_lo(v4) * w4 + bf_lo(v5) * w5 + bf_lo(v6) * w6 + bf_lo(v7) * w7;
        acc.y += bf_hi(v0) * w0 + bf_hi(v1) * w1 + bf_hi(v2) * w2 + bf_hi(v3) * w3
               + bf_hi(v4) * w4 + bf_hi(v5) * w5 + bf_hi(v6) * w6 + bf_hi(v7) * w7;
    }
    for (; j < end; j++) {
        u32 r0 = recs[j];
        u32 v0 = rows[(r0 & 0xffffu) * 64 + lane];
        float w0 = __uint_as_float(r0 & 0xffff0000u);
        acc.x += bf_lo(v0) * w0;
        acc.y += bf_hi(v0) * w0;
    }
    u32 o = ((u32)f2bf(acc.y) << 16) | (u32)f2bf(acc.x);
    ((u32*)Ah)[node * 64 + lane] = o;
}

// ---------------- BN stats from row-major bf16: per-channel sum & sumsq ----------------
__global__ __launch_bounds__(256) void k_stats(const u16* __restrict__ Ah,
                                               float* __restrict__ stats) {
    __shared__ float sh[4][256];
    int t = threadIdx.x;
    int jc = t & 63, ro = t >> 6;         // jc: u32-column (channels 2jc,2jc+1)
    const u32* col = (const u32*)Ah + jc;
    float sx = 0.f, sy = 0.f, qx = 0.f, qy = 0.f;
    for (int r = blockIdx.x * 4 + ro; r < Nn; r += 1024) {
        u32 v = col[r * 64];
        float a = bf_lo(v), b = bf_hi(v);
        sx += a; sy += b; qx += a * a; qy += b * b;
    }
    sh[0][t] = sx; sh[1][t] = sy; sh[2][t] = qx; sh[3][t] = qy;
    __syncthreads();
    if (t < 64) {
        sx = sh[0][t] + sh[0][t + 64] + sh[0][t + 128] + sh[0][t + 192];
        sy = sh[1][t] + sh[1][t + 64] + sh[1][t + 128] + sh[1][t + 192];
        qx = sh[2][t] + sh[2][t + 64] + sh[2][t + 128] + sh[2][t + 192];
        qy = sh[3][t] + sh[3][t + 64] + sh[3][t + 128] + sh[3][t + 192];
        atomicAdd(&stats[2 * t], sx);
        atomicAdd(&stats[2 * t + 1], sy);
        atomicAdd(&stats[Hh + 2 * t], qx);
        atomicAdd(&stats[Hh + 2 * t + 1], qy);
    }
}

// ---------------- BN normalize + affine + relu; row-major bf16 in ----------------
// out: bf16 row-major Xh (layers 0,1) OR fp32 row-major Xo (layer 2)
__global__ void k_norm(const u16* __restrict__ Ah, const float* __restrict__ stats,
                       const float* __restrict__ gam, const float* __restrict__ bet,
                       float* __restrict__ Xo, u16* __restrict__ Xh, int wf32) {
    int tid = blockIdx.x * blockDim.x + threadIdx.x;
    if (tid >= Nn * 32) return;
    int c4 = tid & 31;
    uint2 a = ((const uint2*)Ah)[tid];
    float vv[4] = { bf_lo(a.x), bf_hi(a.x), bf_lo(a.y), bf_hi(a.y) };
    float4 o;
#pragma unroll
    for (int j = 0; j < 4; j++) {
        int c = c4 * 4 + j;
        float mu = stats[c] * (1.0f / Nn);
        float var = stats[Hh + c] * (1.0f / Nn) - mu * mu;
        float istd = rsqrtf(var + EPSf);
        float val = (vv[j] - mu) * istd * gam[c] + bet[c];
        (&o.x)[j] = fmaxf(val, 0.0f);
    }
    if (wf32) {
        ((float4*)Xo)[tid] = o;
    } else {
        ushort4 h;
        h.x = f2bf(o.x); h.y = f2bf(o.y); h.z = f2bf(o.z); h.w = f2bf(o.w);
        ((ushort4*)Xh)[tid] = h;
    }
}

// ---------------- fused segmented mean pool + MLP head: one block per graph ----------------
__global__ __launch_bounds__(128) void k_poolmlp(const float* __restrict__ X,
                                                 const int* __restrict__ gstart,
                                                 const float* __restrict__ W1,
                                                 const float* __restrict__ b1,
                                                 const float* __restrict__ W2,
                                                 const float* __restrict__ b2,
                                                 float* __restrict__ out) {
    int g = blockIdx.x;
    int c = threadIdx.x;
    __shared__ float p[Hh];
    __shared__ float hid[Hh];
    int s = gstart[g], e = gstart[g + 1];
    float sum = 0.0f;
    for (int r = s; r < e; r++) sum += X[r * Hh + c];
    int n = e - s;
    p[c] = sum / (float)(n > 1 ? n : 1);
    __syncthreads();
    float acc = b1[c];
    for (int k = 0; k < Hh; k++) acc += p[k] * W1[k * Hh + c];
    hid[c] = fmaxf(acc, 0.0f);
    __syncthreads();
    if (c < Cc) {
        float acc2 = b2[c];
        for (int k = 0; k < Hh; k++) acc2 += hid[k] * W2[k * Cc + c];
        out[g * Cc + c] = acc2;
    }
}

extern "C" void kernel_launch(void* const* d_in, const int* in_sizes, int n_in,
                              void* d_out, int out_size, void* d_ws, size_t ws_size,
                              hipStream_t stream) {
    const float* x      = (const float*)d_in[0];
    const int*   ei     = (const int*)d_in[1];
    const int*   batch  = (const int*)d_in[2];
    const float* conv_w = (const float*)d_in[3];
    const float* conv_b = (const float*)d_in[4];
    const float* bn_g   = (const float*)d_in[5];
    const float* bn_b   = (const float*)d_in[6];
    const float* w1     = (const float*)d_in[7];
    const float* b1     = (const float*)d_in[8];
    const float* w2     = (const float*)d_in[9];
    const float* b2     = (const float*)d_in[10];
    float* out = (float*)d_out;

    // B1 (fp32, layer-2 output for pooling) aliases Xh (bf16 gemm input):
    // Xh is dead after gemm[l=2]; norm[l=2] then writes B1.
    float* B1      = (float*)d_ws;                // N*H fp32  (aliases Xh region)
    u16*   Xh      = (u16*)d_ws;                  // N*H bf16  (first half of B1 region)
    u16*   Yh      = (u16*)(B1 + Nn * Hh);        // N*H bf16 row-major (gemm out)
    u16*   Ah      = Yh + Nn * Hh;                // N*H bf16 row-major (gather out)
    u16*   WT      = Ah + Nn * Hh;                // 3*H*H bf16 (W^T)
    float* dis     = (float*)(WT + 3 * Hh * Hh);  // N
    float* stats3  = dis + Nn;                    // 3*2*H
    int*   indeg   = (int*)(stats3 + 3 * 2 * Hh); // N
    int*   rs      = indeg + Nn;                  // N
    int*   gstart  = rs + Nn;                     // G+1
    int*   bsum    = gstart + Gg + 1;             // NSB
    u32*   recs    = (u32*)(bsum + NSB);          // E packed 4B records

    // ---- fused prologue + CSR build ----
    k_pre<<<(Nn * 32 + 255) / 256, 256, 0, stream>>>(x, Xh, conv_w, WT, indeg, stats3);
    k_deg<<<(Ee + 255) / 256, 256, 0, stream>>>(ei, indeg);
    k_scan1<<<NSB, 256, 0, stream>>>(indeg, rs, bsum, dis, batch, gstart);
    k_scan2<<<(Nn + 255) / 256, 256, 0, stream>>>(rs, bsum);
    k_fill<<<(Ee + 255) / 256, 256, 0, stream>>>(ei, rs, dis, recs);

    for (int l = 0; l < 3; l++) {
        float* stats = stats3 + l * 2 * Hh;
        k_gemm<<<(Nn + 63) / 64, 256, 0, stream>>>(Xh, WT + l * Hh * Hh, Yh);
        k_gather<<<(Nn + 3) / 4, 256, 0, stream>>>(Yh, dis, conv_b + l * Hh, rs,
                                                   recs, Ah);
        k_stats<<<256, 256, 0, stream>>>(Ah, stats);
        k_norm<<<(Nn * 32 + 255) / 256, 256, 0, stream>>>(
            Ah, stats, bn_g + l * Hh, bn_b + l * Hh,
            B1, Xh, (l == 2) ? 1 : 0);
    }

    k_poolmlp<<<Gg, 128, 0, stream>>>(B1, gstart, w1, b1, w2, b2, out);
}

// Round 10
// 410.451 us; speedup vs baseline: 1.6245x; 1.0670x over previous
//
#include <hip/hip_runtime.h>

#define Nn 50000
#define Ee 800000
#define Gg 1000
#define Hh 128
#define Cc 6
#define EPSf 1e-5f
#define SB 1024                       // elements per scan block
#define NSB ((Nn + SB - 1) / SB)      // 49

typedef unsigned short u16;
typedef unsigned int u32;
typedef __attribute__((ext_vector_type(8))) short bf16x8;
typedef __attribute__((ext_vector_type(4))) float f32x4;

static __device__ inline u16 f2bf(float f) {
    u32 u = __float_as_uint(f);
    u32 r = (u + 0x7fffu + ((u >> 16) & 1u)) >> 16;   // RNE
    return (u16)r;
}
static __device__ inline float bf_lo(u32 v) { return __uint_as_float(v << 16); }
static __device__ inline float bf_hi(u32 v) { return __uint_as_float(v & 0xffff0000u); }
static __device__ inline u32 pack2(float a, float b) {
    return ((u32)f2bf(b) << 16) | (u32)f2bf(a);
}

// ---------------- fused prologue: zero indeg+stats, cast x->bf16, W->bf16 W^T ----------------
__global__ __launch_bounds__(256) void k_pre(const float* __restrict__ X,
                                             u16* __restrict__ Xh,
                                             const float* __restrict__ W3,
                                             u16* __restrict__ WT3,
                                             int* __restrict__ indeg,
                                             float* __restrict__ stats3) {
    int t = blockIdx.x * blockDim.x + threadIdx.x;
    if (t < Nn * 32) {                 // cast x (float4 granular)
        float4 v = ((const float4*)X)[t];
        ushort4 o;
        o.x = f2bf(v.x); o.y = f2bf(v.y); o.z = f2bf(v.z); o.w = f2bf(v.w);
        ((ushort4*)Xh)[t] = o;
    }
    if (t < Nn) indeg[t] = 0;
    if (t < 3 * 2 * Hh) stats3[t] = 0.0f;

    if (blockIdx.x < 3) {              // weight transpose for layer l = blockIdx.x
        __shared__ u16 tbuf[Hh * 136];
        int l = blockIdx.x;
        const float* W = W3 + l * Hh * Hh;
        u16* WT = WT3 + l * Hh * Hh;
        int tid = threadIdx.x;
#pragma unroll
        for (int i = 0; i < 16; i++) {
            int v = tid + 256 * i;     // float4 idx over 4096
            int r = v >> 5, c4 = v & 31;
            float4 d = ((const float4*)W)[v];
            u16* p = tbuf + r * 136 + c4 * 4;
            p[0] = f2bf(d.x); p[1] = f2bf(d.y); p[2] = f2bf(d.z); p[3] = f2bf(d.w);
        }
        __syncthreads();
#pragma unroll
        for (int i = 0; i < 64; i++) {
            int o = tid + 256 * i;     // u16 idx over 16384
            int n = o >> 7, k = o & 127;
            WT[o] = tbuf[k * 136 + n];
        }
    }
}

// ---------------- in-degree histogram ----------------
__global__ void k_deg(const int* __restrict__ ei, int* __restrict__ indeg) {
    int e = blockIdx.x * blockDim.x + threadIdx.x;
    if (e < Ee) atomicAdd(&indeg[ei[Ee + e]], 1);
}

// ---------------- scan phase 1 + dis + gstart (fused) ----------------
__global__ __launch_bounds__(256) void k_scan1(const int* __restrict__ indeg,
                                               int* __restrict__ rs,
                                               int* __restrict__ bsum,
                                               float* __restrict__ dis,
                                               const int* __restrict__ batch,
                                               int* __restrict__ gstart) {
    __shared__ int ts[256];
    int b = blockIdx.x;
    int t = threadIdx.x;
    int base = b * SB + t * 4;
    int v[4] = {0, 0, 0, 0};
#pragma unroll
    for (int j = 0; j < 4; j++) {
        int i = base + j;
        if (i < Nn) { v[j] = indeg[i]; dis[i] = rsqrtf((float)v[j] + 1.0f); }
    }
    int g = b * 256 + t;
    if (g <= Gg) {
        int lo = 0, hi = Nn;
        while (lo < hi) {
            int mid = (lo + hi) >> 1;
            if (batch[mid] < g) lo = mid + 1; else hi = mid;
        }
        gstart[g] = lo;
    }
    int tsum = v[0] + v[1] + v[2] + v[3];
    ts[t] = tsum;
    __syncthreads();
    for (int off = 1; off < 256; off <<= 1) {
        int x = (t >= off) ? ts[t - off] : 0;
        __syncthreads();
        ts[t] += x;
        __syncthreads();
    }
    int run = (t == 0) ? 0 : ts[t - 1];
    if (t == 255) bsum[b] = ts[255];
#pragma unroll
    for (int j = 0; j < 4; j++) {
        int i = base + j;
        if (i < Nn) { rs[i] = run; run += v[j]; }
    }
}

// ---------------- scan phase 2: per-block redundant top-scan + add ----------------
__global__ __launch_bounds__(256) void k_scan2(int* __restrict__ rs,
                                               const int* __restrict__ bsum) {
    __shared__ int lboff[NSB];
    int t = threadIdx.x;
    if (t < 64) {
        int orig = (t < NSB) ? bsum[t] : 0;
        int v = orig;
#pragma unroll
        for (int off = 1; off < 64; off <<= 1) {
            int u = __shfl_up(v, off, 64);
            if (t >= off) v += u;
        }
        if (t < NSB) lboff[t] = v - orig;   // exclusive
    }
    __syncthreads();
    int i = blockIdx.x * blockDim.x + t;
    if (i < Nn) rs[i] += lboff[i >> 10];
}

// ---------------- counting-sort fill: 4B packed {w:bf16 | src:u16} ----------------
// After this kernel rs[d] == end of segment d.
__global__ void k_fill(const int* __restrict__ ei, int* __restrict__ rs,
                       const float* __restrict__ dis, u32* __restrict__ recs) {
    int e = blockIdx.x * blockDim.x + threadIdx.x;
    if (e >= Ee) return;
    int s = ei[e];
    int d = ei[Ee + e];
    int slot = atomicAdd(&rs[d], 1);
    float w = dis[s] * dis[d];
    recs[slot] = ((u32)f2bf(w) << 16) | (u32)s;   // s < 50000 < 65536
}

// ---------------- MFMA GEMM with optional fused BN-normalize on the A-path ----------------
// donorm=0: Xin is ready bf16. donorm=1: Xin is raw aggregation (bf16); apply
// relu(v*scale+shift) with scale/shift derived from prev layer's stats (LDS).
__global__ __launch_bounds__(256) void k_gemm(const u16* __restrict__ Xin,
                                              const u16* __restrict__ WT,
                                              u16* __restrict__ Yh,
                                              const float* __restrict__ stats,
                                              const float* __restrict__ gam,
                                              const float* __restrict__ bet,
                                              int donorm) {
    __shared__ u16 wt[Hh * 136];
    __shared__ float s_scale[Hh], s_shift[Hh];
    int tid = threadIdx.x;
    if (donorm && tid < Hh) {
        float mu = stats[tid] * (1.0f / Nn);
        float var = stats[Hh + tid] * (1.0f / Nn) - mu * mu;
        float sc = rsqrtf(var + EPSf) * gam[tid];
        s_scale[tid] = sc;
        s_shift[tid] = bet[tid] - mu * sc;
    }
#pragma unroll
    for (int i = 0; i < 8; i++) {
        int v = tid + 256 * i;            // uint4 idx over 2048
        int n = v >> 4, k8 = v & 15;
        uint4 d = ((const uint4*)WT)[v];
        *((uint4*)(wt + n * 136 + k8 * 8)) = d;
    }
    __syncthreads();

    int wv = tid >> 6, lane = tid & 63;
    int m = lane & 15, q = lane >> 4;
    int row0 = blockIdx.x * 64 + wv * 16;
    int lrow = row0 + m;
    if (lrow >= Nn) lrow = Nn - 1;        // clamp load row; stores guarded
    const u16* xrow = Xin + lrow * Hh + q * 8;

    f32x4 acc[8] = {};
#pragma unroll
    for (int k0 = 0; k0 < Hh; k0 += 32) {
        bf16x8 a;
        if (donorm) {
            int cb = k0 + q * 8;
            uint4 p = *(const uint4*)(xrow + k0);
            float4 sc0 = *(const float4*)(s_scale + cb);
            float4 sc1 = *(const float4*)(s_scale + cb + 4);
            float4 sh0 = *(const float4*)(s_shift + cb);
            float4 sh1 = *(const float4*)(s_shift + cb + 4);
            float f0 = fmaxf(bf_lo(p.x) * sc0.x + sh0.x, 0.0f);
            float f1 = fmaxf(bf_hi(p.x) * sc0.y + sh0.y, 0.0f);
            float f2 = fmaxf(bf_lo(p.y) * sc0.z + sh0.z, 0.0f);
            float f3 = fmaxf(bf_hi(p.y) * sc0.w + sh0.w, 0.0f);
            float f4 = fmaxf(bf_lo(p.z) * sc1.x + sh1.x, 0.0f);
            float f5 = fmaxf(bf_hi(p.z) * sc1.y + sh1.y, 0.0f);
            float f6 = fmaxf(bf_lo(p.w) * sc1.z + sh1.z, 0.0f);
            float f7 = fmaxf(bf_hi(p.w) * sc1.w + sh1.w, 0.0f);
            union { bf16x8 v; u32 u[4]; } cv;
            cv.u[0] = pack2(f0, f1);
            cv.u[1] = pack2(f2, f3);
            cv.u[2] = pack2(f4, f5);
            cv.u[3] = pack2(f6, f7);
            a = cv.v;
        } else {
            a = *(const bf16x8*)(xrow + k0);
        }
#pragma unroll
        for (int t = 0; t < 8; t++) {
            bf16x8 b = *(const bf16x8*)(wt + (t * 16 + m) * 136 + k0 + q * 8);
            acc[t] = __builtin_amdgcn_mfma_f32_16x16x32_bf16(a, b, acc[t], 0, 0, 0);
        }
    }

    int orow0 = row0 + q * 4;
#pragma unroll
    for (int t = 0; t < 8; t++) {
#pragma unroll
        for (int r = 0; r < 4; r++) {
            int rr = orow0 + r;
            if (rr < Nn) Yh[rr * Hh + t * 16 + m] = f2bf(acc[t][r]);
        }
    }
}

// ---------------- CSR gather: one wave/node, predicated unroll-16 ----------------
// Avg degree = 16 -> one fully-parallel 16-load batch covers the typical node.
__global__ __launch_bounds__(256) void k_gather(const u16* __restrict__ Yh,
                                                const float* __restrict__ dis,
                                                const float* __restrict__ bias,
                                                const int* __restrict__ rs,
                                                const u32* __restrict__ recs,
                                                u16* __restrict__ Ah) {
    int node = blockIdx.x * 4 + (threadIdx.x >> 6);
    if (node >= Nn) return;
    int lane = threadIdx.x & 63;

    const u32* rows = (const u32*)Yh;
    float dn = dis[node];
    u32 hv = rows[node * 64 + lane];
    float2 bv = ((const float2*)bias)[lane];
    float sn = dn * dn;
    float2 acc;
    acc.x = bf_lo(hv) * sn + bv.x;
    acc.y = bf_hi(hv) * sn + bv.y;

    int beg = (node == 0) ? 0 : rs[node - 1];
    int end = rs[node];

    for (int j = beg; j < end; j += 16) {
        u32 rec[16]; float wgt[16]; u32 val[16];
#pragma unroll
        for (int i = 0; i < 16; i++) {
            int idx = j + i;
            int cidx = idx < end ? idx : end - 1;
            rec[i] = recs[cidx];
            wgt[i] = (idx < end) ? __uint_as_float(rec[i] & 0xffff0000u) : 0.0f;
        }
#pragma unroll
        for (int i = 0; i < 16; i++) val[i] = rows[(rec[i] & 0xffffu) * 64 + lane];
#pragma unroll
        for (int i = 0; i < 16; i++) {
            acc.x += bf_lo(val[i]) * wgt[i];
            acc.y += bf_hi(val[i]) * wgt[i];
        }
    }
    ((u32*)Ah)[node * 64 + lane] = pack2(acc.x, acc.y);
}

// ---------------- BN stats from row-major bf16: per-channel sum & sumsq ----------------
__global__ __launch_bounds__(256) void k_stats(const u16* __restrict__ Ah,
                                               float* __restrict__ stats) {
    __shared__ float sh[4][256];
    int t = threadIdx.x;
    int jc = t & 63, ro = t >> 6;         // jc: u32-column (channels 2jc,2jc+1)
    const u32* col = (const u32*)Ah + jc;
    float sx = 0.f, sy = 0.f, qx = 0.f, qy = 0.f;
    for (int r = blockIdx.x * 4 + ro; r < Nn; r += 1024) {
        u32 v = col[r * 64];
        float a = bf_lo(v), b = bf_hi(v);
        sx += a; sy += b; qx += a * a; qy += b * b;
    }
    sh[0][t] = sx; sh[1][t] = sy; sh[2][t] = qx; sh[3][t] = qy;
    __syncthreads();
    if (t < 64) {
        sx = sh[0][t] + sh[0][t + 64] + sh[0][t + 128] + sh[0][t + 192];
        sy = sh[1][t] + sh[1][t + 64] + sh[1][t + 128] + sh[1][t + 192];
        qx = sh[2][t] + sh[2][t + 64] + sh[2][t + 128] + sh[2][t + 192];
        qy = sh[3][t] + sh[3][t + 64] + sh[3][t + 128] + sh[3][t + 192];
        atomicAdd(&stats[2 * t], sx);
        atomicAdd(&stats[2 * t + 1], sy);
        atomicAdd(&stats[Hh + 2 * t], qx);
        atomicAdd(&stats[Hh + 2 * t + 1], qy);
    }
}

// ---------------- fused BN-normalize + mean pool + MLP head: one block per graph ----------------
__global__ __launch_bounds__(128) void k_poolmlp(const u16* __restrict__ Ah,
                                                 const float* __restrict__ stats,
                                                 const float* __restrict__ gam,
                                                 const float* __restrict__ bet,
                                                 const int* __restrict__ gstart,
                                                 const float* __restrict__ W1,
                                                 const float* __restrict__ b1,
                                                 const float* __restrict__ W2,
                                                 const float* __restrict__ b2,
                                                 float* __restrict__ out) {
    int g = blockIdx.x;
    int c = threadIdx.x;
    __shared__ float p[Hh];
    __shared__ float hid[Hh];
    float mu = stats[c] * (1.0f / Nn);
    float var = stats[Hh + c] * (1.0f / Nn) - mu * mu;
    float sc = rsqrtf(var + EPSf) * gam[c];
    float sf = bet[c] - mu * sc;
    int s = gstart[g], e = gstart[g + 1];
    float sum = 0.0f;
    for (int r = s; r < e; r++) {
        float v = __uint_as_float((u32)Ah[r * Hh + c] << 16);
        sum += fmaxf(v * sc + sf, 0.0f);
    }
    int n = e - s;
    p[c] = sum / (float)(n > 1 ? n : 1);
    __syncthreads();
    float acc = b1[c];
    for (int k = 0; k < Hh; k++) acc += p[k] * W1[k * Hh + c];
    hid[c] = fmaxf(acc, 0.0f);
    __syncthreads();
    if (c < Cc) {
        float acc2 = b2[c];
        for (int k = 0; k < Hh; k++) acc2 += hid[k] * W2[k * Cc + c];
        out[g * Cc + c] = acc2;
    }
}

extern "C" void kernel_launch(void* const* d_in, const int* in_sizes, int n_in,
                              void* d_out, int out_size, void* d_ws, size_t ws_size,
                              hipStream_t stream) {
    const float* x      = (const float*)d_in[0];
    const int*   ei     = (const int*)d_in[1];
    const int*   batch  = (const int*)d_in[2];
    const float* conv_w = (const float*)d_in[3];
    const float* conv_b = (const float*)d_in[4];
    const float* bn_g   = (const float*)d_in[5];
    const float* bn_b   = (const float*)d_in[6];
    const float* w1     = (const float*)d_in[7];
    const float* b1     = (const float*)d_in[8];
    const float* w2     = (const float*)d_in[9];
    const float* b2     = (const float*)d_in[10];
    float* out = (float*)d_out;

    u16*   Xh      = (u16*)d_ws;                  // N*H bf16 (layer-0 gemm input)
    u16*   Yh      = Xh + Nn * Hh;                // N*H bf16 row-major (gemm out)
    u16*   Ah      = Yh + Nn * Hh;                // N*H bf16 row-major (gather out)
    u16*   WT      = Ah + Nn * Hh;                // 3*H*H bf16 (W^T)
    float* dis     = (float*)(WT + 3 * Hh * Hh);  // N
    float* stats3  = dis + Nn;                    // 3*2*H
    int*   indeg   = (int*)(stats3 + 3 * 2 * Hh); // N
    int*   rs      = indeg + Nn;                  // N
    int*   gstart  = rs + Nn;                     // G+1
    int*   bsum    = gstart + Gg + 1;             // NSB
    u32*   recs    = (u32*)(bsum + NSB);          // E packed 4B records

    // ---- fused prologue + CSR build ----
    k_pre<<<(Nn * 32 + 255) / 256, 256, 0, stream>>>(x, Xh, conv_w, WT, indeg, stats3);
    k_deg<<<(Ee + 255) / 256, 256, 0, stream>>>(ei, indeg);
    k_scan1<<<NSB, 256, 0, stream>>>(indeg, rs, bsum, dis, batch, gstart);
    k_scan2<<<(Nn + 255) / 256, 256, 0, stream>>>(rs, bsum);
    k_fill<<<(Ee + 255) / 256, 256, 0, stream>>>(ei, rs, dis, recs);

    for (int l = 0; l < 3; l++) {
        float* stats = stats3 + l * 2 * Hh;
        const u16* gin = (l == 0) ? Xh : Ah;
        const float* pst = (l == 0) ? stats3 : stats3 + (l - 1) * 2 * Hh;
        const float* pg  = (l == 0) ? bn_g : bn_g + (l - 1) * Hh;
        const float* pb  = (l == 0) ? bn_b : bn_b + (l - 1) * Hh;
        k_gemm<<<(Nn + 63) / 64, 256, 0, stream>>>(gin, WT + l * Hh * Hh, Yh,
                                                   pst, pg, pb, (l == 0) ? 0 : 1);
        k_gather<<<(Nn + 3) / 4, 256, 0, stream>>>(Yh, dis, conv_b + l * Hh, rs,
                                                   recs, Ah);
        k_stats<<<256, 256, 0, stream>>>(Ah, stats);
    }

    k_poolmlp<<<Gg, 128, 0, stream>>>(Ah, stats3 + 2 * 2 * Hh, bn_g + 2 * Hh,
                                      bn_b + 2 * Hh, gstart, w1, b1, w2, b2, out);
}

// Round 11
// 389.049 us; speedup vs baseline: 1.7139x; 1.0550x over previous
//
#include <hip/hip_runtime.h>

#define Nn 50000
#define Ee 800000
#define Gg 1000
#define Hh 128
#define Cc 6
#define EPSf 1e-5f
#define SB 1024                       // elements per scan block
#define NSB ((Nn + SB - 1) / SB)      // 49

typedef unsigned short u16;
typedef unsigned int u32;
typedef __attribute__((ext_vector_type(8))) short bf16x8;
typedef __attribute__((ext_vector_type(4))) float f32x4;

static __device__ inline u16 f2bf(float f) {
    u32 u = __float_as_uint(f);
    u32 r = (u + 0x7fffu + ((u >> 16) & 1u)) >> 16;   // RNE
    return (u16)r;
}
static __device__ inline float bf_lo(u32 v) { return __uint_as_float(v << 16); }
static __device__ inline float bf_hi(u32 v) { return __uint_as_float(v & 0xffff0000u); }
static __device__ inline u32 pack2(float a, float b) {
    return ((u32)f2bf(b) << 16) | (u32)f2bf(a);
}

// ---------------- prologue A: zero indeg+stats, W->bf16 W^T ----------------
__global__ __launch_bounds__(256) void k_pre(const float* __restrict__ W3,
                                             u16* __restrict__ WT3,
                                             int* __restrict__ indeg,
                                             float* __restrict__ stats3) {
    int t = blockIdx.x * blockDim.x + threadIdx.x;
    if (t < Nn) indeg[t] = 0;
    if (t < 3 * 2 * Hh) stats3[t] = 0.0f;

    if (blockIdx.x < 3) {              // weight transpose for layer l = blockIdx.x
        __shared__ u16 tbuf[Hh * 136];
        int l = blockIdx.x;
        const float* W = W3 + l * Hh * Hh;
        u16* WT = WT3 + l * Hh * Hh;
        int tid = threadIdx.x;
#pragma unroll
        for (int i = 0; i < 16; i++) {
            int v = tid + 256 * i;     // float4 idx over 4096
            int r = v >> 5, c4 = v & 31;
            float4 d = ((const float4*)W)[v];
            u16* p = tbuf + r * 136 + c4 * 4;
            p[0] = f2bf(d.x); p[1] = f2bf(d.y); p[2] = f2bf(d.z); p[3] = f2bf(d.w);
        }
        __syncthreads();
#pragma unroll
        for (int i = 0; i < 64; i++) {
            int o = tid + 256 * i;     // u16 idx over 16384
            int n = o >> 7, k = o & 127;
            WT[o] = tbuf[k * 136 + n];
        }
    }
}

// ---------------- prologue B: in-degree histogram + x->bf16 cast (overlapped) ----------------
__global__ void k_deg(const int* __restrict__ ei, int* __restrict__ indeg,
                      const float* __restrict__ X, u16* __restrict__ Xh) {
    int t = blockIdx.x * blockDim.x + threadIdx.x;
    if (t < Nn * 32) {                 // cast x (float4 granular)
        float4 v = ((const float4*)X)[t];
        ushort4 o;
        o.x = f2bf(v.x); o.y = f2bf(v.y); o.z = f2bf(v.z); o.w = f2bf(v.w);
        ((ushort4*)Xh)[t] = o;
    }
    if (t < Ee) atomicAdd(&indeg[ei[Ee + t]], 1);
}

// ---------------- scan phase 1 + dis + gstart (fused) ----------------
__global__ __launch_bounds__(256) void k_scan1(const int* __restrict__ indeg,
                                               int* __restrict__ rs,
                                               int* __restrict__ bsum,
                                               float* __restrict__ dis,
                                               const int* __restrict__ batch,
                                               int* __restrict__ gstart) {
    __shared__ int ts[256];
    int b = blockIdx.x;
    int t = threadIdx.x;
    int base = b * SB + t * 4;
    int v[4] = {0, 0, 0, 0};
#pragma unroll
    for (int j = 0; j < 4; j++) {
        int i = base + j;
        if (i < Nn) { v[j] = indeg[i]; dis[i] = rsqrtf((float)v[j] + 1.0f); }
    }
    int g = b * 256 + t;
    if (g <= Gg) {
        int lo = 0, hi = Nn;
        while (lo < hi) {
            int mid = (lo + hi) >> 1;
            if (batch[mid] < g) lo = mid + 1; else hi = mid;
        }
        gstart[g] = lo;
    }
    int tsum = v[0] + v[1] + v[2] + v[3];
    ts[t] = tsum;
    __syncthreads();
    for (int off = 1; off < 256; off <<= 1) {
        int x = (t >= off) ? ts[t - off] : 0;
        __syncthreads();
        ts[t] += x;
        __syncthreads();
    }
    int run = (t == 0) ? 0 : ts[t - 1];
    if (t == 255) bsum[b] = ts[255];
#pragma unroll
    for (int j = 0; j < 4; j++) {
        int i = base + j;
        if (i < Nn) { rs[i] = run; run += v[j]; }
    }
}

// ---------------- scan phase 2: per-block redundant top-scan + add ----------------
__global__ __launch_bounds__(256) void k_scan2(int* __restrict__ rs,
                                               const int* __restrict__ bsum) {
    __shared__ int lboff[NSB];
    int t = threadIdx.x;
    if (t < 64) {
        int orig = (t < NSB) ? bsum[t] : 0;
        int v = orig;
#pragma unroll
        for (int off = 1; off < 64; off <<= 1) {
            int u = __shfl_up(v, off, 64);
            if (t >= off) v += u;
        }
        if (t < NSB) lboff[t] = v - orig;   // exclusive
    }
    __syncthreads();
    int i = blockIdx.x * blockDim.x + t;
    if (i < Nn) rs[i] += lboff[i >> 10];
}

// ---------------- counting-sort fill: 4B packed {w:bf16 | src:u16} ----------------
// After this kernel rs[d] == end of segment d.
__global__ void k_fill(const int* __restrict__ ei, int* __restrict__ rs,
                       const float* __restrict__ dis, u32* __restrict__ recs) {
    int e = blockIdx.x * blockDim.x + threadIdx.x;
    if (e >= Ee) return;
    int s = ei[e];
    int d = ei[Ee + e];
    int slot = atomicAdd(&rs[d], 1);
    float w = dis[s] * dis[d];
    recs[slot] = ((u32)f2bf(w) << 16) | (u32)s;   // s < 50000 < 65536
}

// ---------------- MFMA GEMM with optional fused BN-normalize on the A-path ----------------
__global__ __launch_bounds__(256) void k_gemm(const u16* __restrict__ Xin,
                                              const u16* __restrict__ WT,
                                              u16* __restrict__ Yh,
                                              const float* __restrict__ stats,
                                              const float* __restrict__ gam,
                                              const float* __restrict__ bet,
                                              int donorm) {
    __shared__ u16 wt[Hh * 136];
    __shared__ float s_scale[Hh], s_shift[Hh];
    int tid = threadIdx.x;
    if (donorm && tid < Hh) {
        float mu = stats[tid] * (1.0f / Nn);
        float var = stats[Hh + tid] * (1.0f / Nn) - mu * mu;
        float sc = rsqrtf(var + EPSf) * gam[tid];
        s_scale[tid] = sc;
        s_shift[tid] = bet[tid] - mu * sc;
    }
#pragma unroll
    for (int i = 0; i < 8; i++) {
        int v = tid + 256 * i;            // uint4 idx over 2048
        int n = v >> 4, k8 = v & 15;
        uint4 d = ((const uint4*)WT)[v];
        *((uint4*)(wt + n * 136 + k8 * 8)) = d;
    }
    __syncthreads();

    int wv = tid >> 6, lane = tid & 63;
    int m = lane & 15, q = lane >> 4;
    int row0 = blockIdx.x * 64 + wv * 16;
    int lrow = row0 + m;
    if (lrow >= Nn) lrow = Nn - 1;        // clamp load row; stores guarded
    const u16* xrow = Xin + lrow * Hh + q * 8;

    f32x4 acc[8] = {};
#pragma unroll
    for (int k0 = 0; k0 < Hh; k0 += 32) {
        bf16x8 a;
        if (donorm) {
            int cb = k0 + q * 8;
            uint4 p = *(const uint4*)(xrow + k0);
            float4 sc0 = *(const float4*)(s_scale + cb);
            float4 sc1 = *(const float4*)(s_scale + cb + 4);
            float4 sh0 = *(const float4*)(s_shift + cb);
            float4 sh1 = *(const float4*)(s_shift + cb + 4);
            float f0 = fmaxf(bf_lo(p.x) * sc0.x + sh0.x, 0.0f);
            float f1 = fmaxf(bf_hi(p.x) * sc0.y + sh0.y, 0.0f);
            float f2 = fmaxf(bf_lo(p.y) * sc0.z + sh0.z, 0.0f);
            float f3 = fmaxf(bf_hi(p.y) * sc0.w + sh0.w, 0.0f);
            float f4 = fmaxf(bf_lo(p.z) * sc1.x + sh1.x, 0.0f);
            float f5 = fmaxf(bf_hi(p.z) * sc1.y + sh1.y, 0.0f);
            float f6 = fmaxf(bf_lo(p.w) * sc1.z + sh1.z, 0.0f);
            float f7 = fmaxf(bf_hi(p.w) * sc1.w + sh1.w, 0.0f);
            union { bf16x8 v; u32 u[4]; } cv;
            cv.u[0] = pack2(f0, f1);
            cv.u[1] = pack2(f2, f3);
            cv.u[2] = pack2(f4, f5);
            cv.u[3] = pack2(f6, f7);
            a = cv.v;
        } else {
            a = *(const bf16x8*)(xrow + k0);
        }
#pragma unroll
        for (int t = 0; t < 8; t++) {
            bf16x8 b = *(const bf16x8*)(wt + (t * 16 + m) * 136 + k0 + q * 8);
            acc[t] = __builtin_amdgcn_mfma_f32_16x16x32_bf16(a, b, acc[t], 0, 0, 0);
        }
    }

    int orow0 = row0 + q * 4;
#pragma unroll
    for (int t = 0; t < 8; t++) {
#pragma unroll
        for (int r = 0; r < 4; r++) {
            int rr = orow0 + r;
            if (rr < Nn) Yh[rr * Hh + t * 16 + m] = f2bf(acc[t][r]);
        }
    }
}

// ---------------- CSR gather: one wave/node, shfl-broadcast recs, unroll 16 ----------------
// One coalesced recs load per 64-edge super-batch; __shfl (LDS pipe) distributes,
// keeping only the 16 row loads on the vmcnt chain.
__global__ __launch_bounds__(256) void k_gather(const u16* __restrict__ Yh,
                                                const float* __restrict__ dis,
                                                const float* __restrict__ bias,
                                                const int* __restrict__ rs,
                                                const u32* __restrict__ recs,
                                                u16* __restrict__ Ah) {
    int node = blockIdx.x * 4 + (threadIdx.x >> 6);
    if (node >= Nn) return;
    int lane = threadIdx.x & 63;

    const u32* rows = (const u32*)Yh;
    float dn = dis[node];
    u32 hv = rows[node * 64 + lane];
    float2 bv = ((const float2*)bias)[lane];
    float sn = dn * dn;
    float2 acc;
    acc.x = bf_lo(hv) * sn + bv.x;
    acc.y = bf_hi(hv) * sn + bv.y;

    int beg = (node == 0) ? 0 : rs[node - 1];
    int end = rs[node];

    for (int base = beg; base < end; base += 64) {
        int me = base + lane;
        u32 myrec = recs[me < end ? me : end - 1];   // one coalesced load / 64 edges
        int cnt = end - base;
        if (cnt > 64) cnt = 64;
        for (int i0 = 0; i0 < cnt; i0 += 16) {
            u32 rec[16]; float wgt[16]; u32 val[16];
#pragma unroll
            for (int i = 0; i < 16; i++) {
                int si = i0 + i;
                int sc = si < cnt ? si : cnt - 1;
                rec[i] = __shfl(myrec, sc, 64);
                wgt[i] = (si < cnt) ? __uint_as_float(rec[i] & 0xffff0000u) : 0.0f;
            }
#pragma unroll
            for (int i = 0; i < 16; i++) val[i] = rows[(rec[i] & 0xffffu) * 64 + lane];
#pragma unroll
            for (int i = 0; i < 16; i++) {
                acc.x += bf_lo(val[i]) * wgt[i];
                acc.y += bf_hi(val[i]) * wgt[i];
            }
        }
    }
    __builtin_nontemporal_store(pack2(acc.x, acc.y), (u32*)Ah + node * 64 + lane);
}

// ---------------- BN stats from row-major bf16: per-channel sum & sumsq, unroll 4 ----------------
__global__ __launch_bounds__(256) void k_stats(const u16* __restrict__ Ah,
                                               float* __restrict__ stats) {
    __shared__ float sh[4][256];
    int t = threadIdx.x;
    int jc = t & 63, ro = t >> 6;         // jc: u32-column (channels 2jc,2jc+1)
    const u32* col = (const u32*)Ah + jc;
    float sx = 0.f, sy = 0.f, qx = 0.f, qy = 0.f;
    for (int r = blockIdx.x * 16 + ro * 4; r < Nn; r += 4096) {
        u32 v[4];
#pragma unroll
        for (int k = 0; k < 4; k++) {
            int rr = r + k;
            v[k] = (rr < Nn) ? col[rr * 64] : 0u;
        }
#pragma unroll
        for (int k = 0; k < 4; k++) {
            float a = bf_lo(v[k]), b = bf_hi(v[k]);
            sx += a; sy += b; qx += a * a; qy += b * b;
        }
    }
    sh[0][t] = sx; sh[1][t] = sy; sh[2][t] = qx; sh[3][t] = qy;
    __syncthreads();
    if (t < 64) {
        sx = sh[0][t] + sh[0][t + 64] + sh[0][t + 128] + sh[0][t + 192];
        sy = sh[1][t] + sh[1][t + 64] + sh[1][t + 128] + sh[1][t + 192];
        qx = sh[2][t] + sh[2][t + 64] + sh[2][t + 128] + sh[2][t + 192];
        qy = sh[3][t] + sh[3][t + 64] + sh[3][t + 128] + sh[3][t + 192];
        atomicAdd(&stats[2 * t], sx);
        atomicAdd(&stats[2 * t + 1], sy);
        atomicAdd(&stats[Hh + 2 * t], qx);
        atomicAdd(&stats[Hh + 2 * t + 1], qy);
    }
}

// ---------------- fused BN-normalize + mean pool + MLP head: one block per graph ----------------
__global__ __launch_bounds__(128) void k_poolmlp(const u16* __restrict__ Ah,
                                                 const float* __restrict__ stats,
                                                 const float* __restrict__ gam,
                                                 const float* __restrict__ bet,
                                                 const int* __restrict__ gstart,
                                                 const float* __restrict__ W1,
                                                 const float* __restrict__ b1,
                                                 const float* __restrict__ W2,
                                                 const float* __restrict__ b2,
                                                 float* __restrict__ out) {
    int g = blockIdx.x;
    int c = threadIdx.x;
    __shared__ float p[Hh];
    __shared__ float hid[Hh];
    float mu = stats[c] * (1.0f / Nn);
    float var = stats[Hh + c] * (1.0f / Nn) - mu * mu;
    float sc = rsqrtf(var + EPSf) * gam[c];
    float sf = bet[c] - mu * sc;
    int s = gstart[g], e = gstart[g + 1];
    float sum = 0.0f;
    for (int r = s; r < e; r++) {
        float v = __uint_as_float((u32)Ah[r * Hh + c] << 16);
        sum += fmaxf(v * sc + sf, 0.0f);
    }
    int n = e - s;
    p[c] = sum / (float)(n > 1 ? n : 1);
    __syncthreads();
    float acc = b1[c];
    for (int k = 0; k < Hh; k++) acc += p[k] * W1[k * Hh + c];
    hid[c] = fmaxf(acc, 0.0f);
    __syncthreads();
    if (c < Cc) {
        float acc2 = b2[c];
        for (int k = 0; k < Hh; k++) acc2 += hid[k] * W2[k * Cc + c];
        out[g * Cc + c] = acc2;
    }
}

extern "C" void kernel_launch(void* const* d_in, const int* in_sizes, int n_in,
                              void* d_out, int out_size, void* d_ws, size_t ws_size,
                              hipStream_t stream) {
    const float* x      = (const float*)d_in[0];
    const int*   ei     = (const int*)d_in[1];
    const int*   batch  = (const int*)d_in[2];
    const float* conv_w = (const float*)d_in[3];
    const float* conv_b = (const float*)d_in[4];
    const float* bn_g   = (const float*)d_in[5];
    const float* bn_b   = (const float*)d_in[6];
    const float* w1     = (const float*)d_in[7];
    const float* b1     = (const float*)d_in[8];
    const float* w2     = (const float*)d_in[9];
    const float* b2     = (const float*)d_in[10];
    float* out = (float*)d_out;

    u16*   Xh      = (u16*)d_ws;                  // N*H bf16 (layer-0 gemm input)
    u16*   Yh      = Xh + Nn * Hh;                // N*H bf16 row-major (gemm out)
    u16*   Ah      = Yh + Nn * Hh;                // N*H bf16 row-major (gather out)
    u16*   WT      = Ah + Nn * Hh;                // 3*H*H bf16 (W^T)
    float* dis     = (float*)(WT + 3 * Hh * Hh);  // N
    float* stats3  = dis + Nn;                    // 3*2*H
    int*   indeg   = (int*)(stats3 + 3 * 2 * Hh); // N
    int*   rs      = indeg + Nn;                  // N
    int*   gstart  = rs + Nn;                     // G+1
    int*   bsum    = gstart + Gg + 1;             // NSB
    u32*   recs    = (u32*)(bsum + NSB);          // E packed 4B records

    // ---- prologue + CSR build ----
    k_pre<<<(Nn + 255) / 256, 256, 0, stream>>>(conv_w, WT, indeg, stats3);
    k_deg<<<(Nn * 32 + 255) / 256, 256, 0, stream>>>(ei, indeg, x, Xh);
    k_scan1<<<NSB, 256, 0, stream>>>(indeg, rs, bsum, dis, batch, gstart);
    k_scan2<<<(Nn + 255) / 256, 256, 0, stream>>>(rs, bsum);
    k_fill<<<(Ee + 255) / 256, 256, 0, stream>>>(ei, rs, dis, recs);

    for (int l = 0; l < 3; l++) {
        float* stats = stats3 + l * 2 * Hh;
        const u16* gin = (l == 0) ? Xh : Ah;
        const float* pst = (l == 0) ? stats3 : stats3 + (l - 1) * 2 * Hh;
        const float* pg  = (l == 0) ? bn_g : bn_g + (l - 1) * Hh;
        const float* pb  = (l == 0) ? bn_b : bn_b + (l - 1) * Hh;
        k_gemm<<<(Nn + 63) / 64, 256, 0, stream>>>(gin, WT + l * Hh * Hh, Yh,
                                                   pst, pg, pb, (l == 0) ? 0 : 1);
        k_gather<<<(Nn + 3) / 4, 256, 0, stream>>>(Yh, dis, conv_b + l * Hh, rs,
                                                   recs, Ah);
        k_stats<<<256, 256, 0, stream>>>(Ah, stats);
    }

    k_poolmlp<<<Gg, 128, 0, stream>>>(Ah, stats3 + 2 * 2 * Hh, bn_g + 2 * Hh,
                                      bn_b + 2 * Hh, gstart, w1, b1, w2, b2, out);
}